// Round 1
// baseline (437.436 us; speedup 1.0000x reference)
//
#include <hip/hip_runtime.h>
#include <cstdint>
#include <cstddef>

typedef _Float16 f16;
typedef f16 f16x4 __attribute__((ext_vector_type(4)));
typedef f16 f16x8 __attribute__((ext_vector_type(8)));
typedef float f32x4 __attribute__((ext_vector_type(4)));

#define NB    64      // batch
#define NPOMO 200
#define NNODE 201
#define NEMB  512
#define NH    16
#define ND    32

__device__ __forceinline__ void gload16(const void* g, void* l) {
  __builtin_amdgcn_global_load_lds((const __attribute__((address_space(1))) void*)g,
                                   (__attribute__((address_space(3))) void*)l, 16, 0, 0);
}

// ---------------- cast / layout kernels ----------------

__global__ void cast_x(const float* __restrict__ x, f16* __restrict__ o, int n4) {
  int i = blockIdx.x * 256 + threadIdx.x;
  if (i < n4) {
    float4 v = ((const float4*)x)[i];
    f16x4 h = {(f16)v.x, (f16)v.y, (f16)v.z, (f16)v.w};
    ((f16x4*)o)[i] = h;
  }
}

// Qcat: (12800 x 1024) fp16, cols 0..511 = encoded_q1 row, 512..1023 = encoded_last_node row
__global__ void build_qcat(const float* __restrict__ q1, const float* __restrict__ ql,
                           f16* __restrict__ o) {
  int i = blockIdx.x * 256 + threadIdx.x;   // over 4-element groups; 12800*256 total
  if (i >= 12800 * 256) return;
  int row = i >> 8;
  int g = i & 255;
  const float* src = (g < 128) ? (q1 + (size_t)row * 512 + g * 4)
                               : (ql + (size_t)row * 512 + (g - 128) * 4);
  float4 v = *(const float4*)src;
  f16x4 h = {(f16)v.x, (f16)v.y, (f16)v.z, (f16)v.w};
  ((f16x4*)o)[i] = h;
}

// WkvT (1024x512): row j<512 -> Wk[:,j]; j>=512 -> Wv[:,j-512]
// WqcatT (512x1024): [j][k] = k<512 ? Wqf[k][j] : Wql[k-512][j]
// WcT (512x512): [j][k] = Wc[k][j]
__global__ void build_w(const float* __restrict__ Wk, const float* __restrict__ Wv,
                        const float* __restrict__ Wqf, const float* __restrict__ Wql,
                        const float* __restrict__ Wc,
                        f16* __restrict__ wkvT, f16* __restrict__ wqT, f16* __restrict__ wcT) {
  int i = blockIdx.x * 256 + threadIdx.x;
  if (i < 524288) {                       // WkvT
    int j = i >> 9, k = i & 511;
    float v = (j < 512) ? Wk[(size_t)k * 512 + j] : Wv[(size_t)k * 512 + (j - 512)];
    wkvT[i] = (f16)v;
  } else if (i < 1048576) {               // WqcatT
    int t = i - 524288;
    int j = t >> 10, k = t & 1023;
    float v = (k < 512) ? Wqf[(size_t)k * 512 + j] : Wql[(size_t)(k - 512) * 512 + j];
    wqT[t] = (f16)v;
  } else if (i < 1310720) {               // WcT
    int t = i - 1048576;
    int j = t >> 9, k = t & 511;
    wcT[t] = (f16)Wc[(size_t)k * 512 + j];
  }
}

// ---------------- generic GEMM: C(MxN) = A(MxK) * B(NxK)^T (+bias), fp16 out ----------------
// 128x128 block tile, BK=64, 256 threads (2x2 waves of 64x64), global_load_lds staging
// with XOR-swizzled 16B chunks (8 chunks/row of 64 f16).

__global__ __launch_bounds__(256, 2) void gemm_tn(
    const f16* __restrict__ A, const f16* __restrict__ B, f16* __restrict__ C,
    const float* __restrict__ bias, int M, int N, int K) {
  __shared__ f16 As[128 * 64];
  __shared__ f16 Bs[128 * 64];
  const int tid = threadIdx.x;
  const int wave = tid >> 6, lane = tid & 63;
  const int qd = lane >> 4, c = lane & 15;
  const int wm = wave >> 1, wn = wave & 1;
  const int m0 = blockIdx.x * 128, n0 = blockIdx.y * 128;
  const int srow = lane >> 3, sj = lane & 7;

  f32x4 acc[4][4];
#pragma unroll
  for (int i = 0; i < 4; ++i)
#pragma unroll
    for (int j = 0; j < 4; ++j) acc[i][j] = (f32x4){0.f, 0.f, 0.f, 0.f};

  for (int kc = 0; kc < K; kc += 64) {
#pragma unroll
    for (int i = 0; i < 4; ++i) {   // A: wave stages rows wave*32+i*8 .. +7
      int row = wave * 32 + i * 8 + srow;
      int gr = m0 + row; if (gr >= M) gr = M - 1;
      int gj = sj ^ (row & 7);
      gload16(A + (size_t)gr * K + kc + gj * 8, As + row * 64 + sj * 8);
    }
#pragma unroll
    for (int i = 0; i < 4; ++i) {   // B (N always multiple of 128)
      int row = wave * 32 + i * 8 + srow;
      int gj = sj ^ (row & 7);
      gload16(B + (size_t)(n0 + row) * K + kc + gj * 8, Bs + row * 64 + sj * 8);
    }
    __syncthreads();
#pragma unroll
    for (int kk = 0; kk < 2; ++kk) {
      f16x8 af[4], bf[4];
#pragma unroll
      for (int t = 0; t < 4; ++t) {
        int ra = wm * 64 + t * 16 + c;
        af[t] = *(const f16x8*)(As + ra * 64 + (((kk * 4 + qd) ^ (ra & 7)) * 8));
        int rb = wn * 64 + t * 16 + c;
        bf[t] = *(const f16x8*)(Bs + rb * 64 + (((kk * 4 + qd) ^ (rb & 7)) * 8));
      }
#pragma unroll
      for (int mt = 0; mt < 4; ++mt)
#pragma unroll
        for (int nt = 0; nt < 4; ++nt)
          acc[mt][nt] = __builtin_amdgcn_mfma_f32_16x16x32_f16(af[mt], bf[nt], acc[mt][nt], 0, 0, 0);
    }
    __syncthreads();
  }

#pragma unroll
  for (int mt = 0; mt < 4; ++mt) {
#pragma unroll
    for (int nt = 0; nt < 4; ++nt) {
      int col = n0 + wn * 64 + nt * 16 + c;
      float bv = bias ? bias[col] : 0.0f;
#pragma unroll
      for (int r = 0; r < 4; ++r) {
        int row = m0 + wm * 64 + mt * 16 + qd * 4 + r;
        if (row < M) C[(size_t)row * N + col] = (f16)(acc[mt][nt][r] + bv);
      }
    }
  }
}

// ---------------- fused multi-head attention ----------------
// one block per (b,h); 4 waves; each wave owns 16-row tiles rt = wave, wave+4, ...
// K in LDS (stride 40), V^T in LDS (stride 232), P round-trip via per-wave LDS tile.

__global__ __launch_bounds__(256, 2) void attn_kernel(
    const f16* __restrict__ Qp, const f16* __restrict__ KV,
    const float* __restrict__ mask, f16* __restrict__ Oc) {
  __shared__ f16 Ks[208 * 40];
  __shared__ f16 Vt[32 * 232];
  __shared__ f16 Ps[4 * 16 * 232];
  const int b = blockIdx.x >> 4, h = blockIdx.x & 15;
  const int tid = threadIdx.x;
  const int wave = tid >> 6, lane = tid & 63;
  const int qd = lane >> 4, c = lane & 15;

  for (int idx = tid; idx < 208 * 8; idx += 256) {   // K rows 0..200, pad->0
    int row = idx >> 3, ch = idx & 7;
    f16x4 v = (f16x4){0, 0, 0, 0};
    if (row < 201) v = *(const f16x4*)(KV + ((size_t)(b * NNODE + row)) * 1024 + h * 32 + ch * 4);
    *(f16x4*)(Ks + row * 40 + ch * 4) = v;
  }
  for (int idx = tid; idx < 224 * 8; idx += 256) {   // V transposed, m 0..223 (pad->0)
    int m = idx >> 3, ch = idx & 7;
    f16x4 v = (f16x4){0, 0, 0, 0};
    if (m < 201) v = *(const f16x4*)(KV + ((size_t)(b * NNODE + m)) * 1024 + 512 + h * 32 + ch * 4);
    Vt[(ch * 4 + 0) * 232 + m] = v.x;
    Vt[(ch * 4 + 1) * 232 + m] = v.y;
    Vt[(ch * 4 + 2) * 232 + m] = v.z;
    Vt[(ch * 4 + 3) * 232 + m] = v.w;
  }
  for (int i = tid; i < 3712; i += 256) ((f16x4*)Ps)[i] = (f16x4){0, 0, 0, 0};
  __syncthreads();

  f16* Pw = Ps + wave * (16 * 232);
  const float scale = 0.17677669529663687f;   // 1/sqrt(32)

  for (int rt = wave; rt < 13; rt += 4) {
    int qrow = rt * 16 + c; if (qrow > 199) qrow = 199;
    f16x8 aq = *(const f16x8*)(Qp + ((size_t)(b * NPOMO + qrow)) * 512 + h * 32 + qd * 8);
    f32x4 s[13];
#pragma unroll
    for (int nt = 0; nt < 13; ++nt) {
      f16x8 bk = *(const f16x8*)(Ks + (nt * 16 + c) * 40 + qd * 8);
      f32x4 z = (f32x4){0.f, 0.f, 0.f, 0.f};
      s[nt] = __builtin_amdgcn_mfma_f32_16x16x32_f16(aq, bk, z, 0, 0, 0);
    }
    const int rowb = rt * 16 + qd * 4;
    float mx[4] = {-3e38f, -3e38f, -3e38f, -3e38f};
#pragma unroll
    for (int nt = 0; nt < 13; ++nt) {
      int col = nt * 16 + c;
#pragma unroll
      for (int r = 0; r < 4; ++r) {
        float v = s[nt][r] * scale;
        if (col > 200) v = -3e38f;
        else if (col < 200) {
          int rr = rowb + r;
          if (rr < 200) v += mask[((size_t)b * NPOMO + rr) * 200 + col];
        }
        s[nt][r] = v;
        mx[r] = fmaxf(mx[r], v);
      }
    }
#pragma unroll
    for (int off = 8; off >= 1; off >>= 1)
#pragma unroll
      for (int r = 0; r < 4; ++r) mx[r] = fmaxf(mx[r], __shfl_xor(mx[r], off, 16));
    float sm[4] = {0.f, 0.f, 0.f, 0.f};
#pragma unroll
    for (int nt = 0; nt < 13; ++nt)
#pragma unroll
      for (int r = 0; r < 4; ++r) {
        float p = __expf(s[nt][r] - mx[r]);
        s[nt][r] = p;
        sm[r] += p;
      }
#pragma unroll
    for (int off = 8; off >= 1; off >>= 1)
#pragma unroll
      for (int r = 0; r < 4; ++r) sm[r] += __shfl_xor(sm[r], off, 16);
    float inv[4];
#pragma unroll
    for (int r = 0; r < 4; ++r) inv[r] = 1.0f / sm[r];
#pragma unroll
    for (int nt = 0; nt < 13; ++nt)
#pragma unroll
      for (int r = 0; r < 4; ++r)
        Pw[(qd * 4 + r) * 232 + nt * 16 + c] = (f16)(s[nt][r] * inv[r]);

    // O = P(16x201) @ V(201x32)  via B = V^T
    f16x8 pf[7];
#pragma unroll
    for (int kk = 0; kk < 7; ++kk) pf[kk] = *(const f16x8*)(Pw + c * 232 + kk * 32 + qd * 8);
#pragma unroll
    for (int n2 = 0; n2 < 2; ++n2) {
      f32x4 o = (f32x4){0.f, 0.f, 0.f, 0.f};
#pragma unroll
      for (int kk = 0; kk < 7; ++kk) {
        f16x8 bv = *(const f16x8*)(Vt + (n2 * 16 + c) * 232 + kk * 32 + qd * 8);
        o = __builtin_amdgcn_mfma_f32_16x16x32_f16(pf[kk], bv, o, 0, 0, 0);
      }
#pragma unroll
      for (int r = 0; r < 4; ++r) {
        int rr = rt * 16 + qd * 4 + r;
        if (rr < 200) Oc[((size_t)(b * NPOMO + rr)) * 512 + h * 32 + n2 * 16 + c] = (f16)o[r];
      }
    }
  }
}

// ---------------- final: score2 -> 10*tanh + mask -> softmax ----------------
// grid = 64 batches x 4 row-blocks of 64; each wave owns 16 rows, 13 col-tiles (208 cols).

__global__ __launch_bounds__(256, 2) void final_kernel(
    const f16* __restrict__ mh, const f16* __restrict__ Xnh,
    const float* __restrict__ mask, float* __restrict__ out) {
  __shared__ f16 As[64 * 72];
  __shared__ f16 Bs[208 * 72];
  const int b = blockIdx.x >> 2, rb = blockIdx.x & 3;
  const int r0 = rb * 64;
  const int tid = threadIdx.x;
  const int wave = tid >> 6, lane = tid & 63;
  const int qd = lane >> 4, c = lane & 15;

  f32x4 acc[13];
#pragma unroll
  for (int i = 0; i < 13; ++i) acc[i] = (f32x4){0.f, 0.f, 0.f, 0.f};

  for (int kc = 0; kc < 512; kc += 64) {
    for (int idx = tid; idx < 64 * 16; idx += 256) {
      int row = idx >> 4, ch = idx & 15;
      int gr = r0 + row; if (gr > 199) gr = 199;
      *(f16x4*)(As + row * 72 + ch * 4) =
          *(const f16x4*)(mh + ((size_t)b * NPOMO + gr) * 512 + kc + ch * 4);
    }
    for (int idx = tid; idx < 208 * 16; idx += 256) {
      int n = idx >> 4, ch = idx & 15;
      f16x4 v = (f16x4){0, 0, 0, 0};
      if (n < 200) v = *(const f16x4*)(Xnh + ((size_t)b * NNODE + n) * 512 + kc + ch * 4);
      *(f16x4*)(Bs + n * 72 + ch * 4) = v;
    }
    __syncthreads();
#pragma unroll
    for (int kk = 0; kk < 2; ++kk) {
      f16x8 a = *(const f16x8*)(As + (wave * 16 + c) * 72 + kk * 32 + qd * 8);
#pragma unroll
      for (int nt = 0; nt < 13; ++nt) {
        f16x8 bb = *(const f16x8*)(Bs + (nt * 16 + c) * 72 + kk * 32 + qd * 8);
        acc[nt] = __builtin_amdgcn_mfma_f32_16x16x32_f16(a, bb, acc[nt], 0, 0, 0);
      }
    }
    __syncthreads();
  }

  const float invS = 1.0f / 22.627416997969522f;
  const int rowb = r0 + wave * 16 + qd * 4;
  float mx[4] = {-3e38f, -3e38f, -3e38f, -3e38f};
#pragma unroll
  for (int nt = 0; nt < 13; ++nt) {
    int col = nt * 16 + c;
#pragma unroll
    for (int r = 0; r < 4; ++r) {
      float v;
      if (col < 200) {
        v = 10.0f * tanhf(acc[nt][r] * invS);
        int rr = rowb + r;
        if (rr < 200) v += mask[((size_t)b * NPOMO + rr) * 200 + col];
      } else {
        v = -3e38f;
      }
      acc[nt][r] = v;
      mx[r] = fmaxf(mx[r], v);
    }
  }
#pragma unroll
  for (int off = 8; off >= 1; off >>= 1)
#pragma unroll
    for (int r = 0; r < 4; ++r) mx[r] = fmaxf(mx[r], __shfl_xor(mx[r], off, 16));
  float sm[4] = {0.f, 0.f, 0.f, 0.f};
#pragma unroll
  for (int nt = 0; nt < 13; ++nt)
#pragma unroll
    for (int r = 0; r < 4; ++r) {
      float p = __expf(acc[nt][r] - mx[r]);
      acc[nt][r] = p;
      sm[r] += p;
    }
#pragma unroll
  for (int off = 8; off >= 1; off >>= 1)
#pragma unroll
    for (int r = 0; r < 4; ++r) sm[r] += __shfl_xor(sm[r], off, 16);
  float inv[4];
#pragma unroll
  for (int r = 0; r < 4; ++r) inv[r] = 1.0f / sm[r];
#pragma unroll
  for (int nt = 0; nt < 13; ++nt) {
    int col = nt * 16 + c;
#pragma unroll
    for (int r = 0; r < 4; ++r) {
      int rr = rowb + r;
      if (col < 200 && rr < 200)
        out[((size_t)b * NPOMO + rr) * 200 + col] = acc[nt][r] * inv[r];
    }
  }
}

// ---------------- launcher ----------------

extern "C" void kernel_launch(void* const* d_in, const int* in_sizes, int n_in,
                              void* d_out, int out_size, void* d_ws, size_t ws_size,
                              hipStream_t stream) {
  (void)in_sizes; (void)n_in; (void)out_size; (void)ws_size;
  const float* enc   = (const float*)d_in[0];
  const float* q1    = (const float*)d_in[1];
  const float* qlast = (const float*)d_in[2];
  const float* mask  = (const float*)d_in[3];
  const float* Wqf   = (const float*)d_in[4];
  const float* Wql   = (const float*)d_in[5];
  const float* Wk    = (const float*)d_in[6];
  const float* Wv    = (const float*)d_in[7];
  const float* Wc    = (const float*)d_in[8];
  const float* bc    = (const float*)d_in[9];
  float* out = (float*)d_out;

  char* ws = (char*)d_ws;
  f16* Xnh  = (f16*)(ws + 0);           // 12864*512*2  = 13,172,736
  f16* Qcat = (f16*)(ws + 13172736);    // 12800*1024*2 = 26,214,400
  f16* WkvT = (f16*)(ws + 39387136);    // 1024*512*2   =  1,048,576
  f16* WqT  = (f16*)(ws + 40435712);    // 512*1024*2   =  1,048,576
  f16* WcT  = (f16*)(ws + 41484288);    // 512*512*2    =    524,288
  f16* KVp  = (f16*)(ws + 42008576);    // 12864*1024*2 = 26,345,472
  f16* Qp   = (f16*)(ws + 68354048);    // 12800*512*2  = 13,107,200
  f16* Oc   = (f16*)(ws + 81461248);    // 12800*512*2  = 13,107,200
  f16* mhb  = (f16*)(ws + 94568448);    // 12800*512*2  = 13,107,200  (end 107,675,648)

  hipLaunchKernelGGL(cast_x, dim3(6432), dim3(256), 0, stream, enc, Xnh, 1646592);
  hipLaunchKernelGGL(build_qcat, dim3(12800), dim3(256), 0, stream, q1, qlast, Qcat);
  hipLaunchKernelGGL(build_w, dim3(5120), dim3(256), 0, stream, Wk, Wv, Wqf, Wql, Wc, WkvT, WqT, WcT);
  // K,V projection: (12864x512) @ (1024x512)^T -> 12864x1024 (cols 0..511=K, 512..1023=V)
  hipLaunchKernelGGL(gemm_tn, dim3(101, 8), dim3(256), 0, stream,
                     Xnh, WkvT, KVp, (const float*)nullptr, 12864, 1024, 512);
  // Q projection: (12800x1024) @ (512x1024)^T -> 12800x512
  hipLaunchKernelGGL(gemm_tn, dim3(100, 4), dim3(256), 0, stream,
                     Qcat, WqT, Qp, (const float*)nullptr, 12800, 512, 1024);
  hipLaunchKernelGGL(attn_kernel, dim3(1024), dim3(256), 0, stream, Qp, KVp, mask, Oc);
  // Wc projection + bias: (12800x512) @ (512x512)^T + bc -> 12800x512
  hipLaunchKernelGGL(gemm_tn, dim3(100, 4), dim3(256), 0, stream,
                     Oc, WcT, mhb, bc, 12800, 512, 512);
  hipLaunchKernelGGL(final_kernel, dim3(256), dim3(256), 0, stream, mhb, Xnh, mask, out);
}

// Round 2
// 351.569 us; speedup vs baseline: 1.2442x; 1.2442x over previous
//
#include <hip/hip_runtime.h>
#include <cstdint>
#include <cstddef>

typedef _Float16 f16;
typedef f16 f16x4 __attribute__((ext_vector_type(4)));
typedef f16 f16x8 __attribute__((ext_vector_type(8)));
typedef float f32x4 __attribute__((ext_vector_type(4)));

#define NB    64      // batch
#define NPOMO 200
#define NNODE 201
#define NEMB  512
#define NH    16
#define ND    32

__device__ __forceinline__ void gload16(const void* g, void* l) {
  __builtin_amdgcn_global_load_lds((const __attribute__((address_space(1))) void*)g,
                                   (__attribute__((address_space(3))) void*)l, 16, 0, 0);
}

// ---------------- cast / layout kernels ----------------

__global__ void cast_x(const float* __restrict__ x, f16* __restrict__ o, int n4) {
  int i = blockIdx.x * 256 + threadIdx.x;
  if (i < n4) {
    float4 v = ((const float4*)x)[i];
    f16x4 h = {(f16)v.x, (f16)v.y, (f16)v.z, (f16)v.w};
    ((f16x4*)o)[i] = h;
  }
}

// Qcat: (12800 x 1024) fp16, cols 0..511 = encoded_q1 row, 512..1023 = encoded_last_node row
__global__ void build_qcat(const float* __restrict__ q1, const float* __restrict__ ql,
                           f16* __restrict__ o) {
  int i = blockIdx.x * 256 + threadIdx.x;   // over 4-element groups; 12800*256 total
  if (i >= 12800 * 256) return;
  int row = i >> 8;
  int g = i & 255;
  const float* src = (g < 128) ? (q1 + (size_t)row * 512 + g * 4)
                               : (ql + (size_t)row * 512 + (g - 128) * 4);
  float4 v = *(const float4*)src;
  f16x4 h = {(f16)v.x, (f16)v.y, (f16)v.z, (f16)v.w};
  ((f16x4*)o)[i] = h;
}

// WkvT (1024x512): row j<512 -> Wk[:,j]; j>=512 -> Wv[:,j-512]
// WqcatT (512x1024): [j][k] = k<512 ? Wqf[k][j] : Wql[k-512][j]
// WcT (512x512): [j][k] = Wc[k][j]
__global__ void build_w(const float* __restrict__ Wk, const float* __restrict__ Wv,
                        const float* __restrict__ Wqf, const float* __restrict__ Wql,
                        const float* __restrict__ Wc,
                        f16* __restrict__ wkvT, f16* __restrict__ wqT, f16* __restrict__ wcT) {
  int i = blockIdx.x * 256 + threadIdx.x;
  if (i < 524288) {                       // WkvT
    int j = i >> 9, k = i & 511;
    float v = (j < 512) ? Wk[(size_t)k * 512 + j] : Wv[(size_t)k * 512 + (j - 512)];
    wkvT[i] = (f16)v;
  } else if (i < 1048576) {               // WqcatT
    int t = i - 524288;
    int j = t >> 10, k = t & 1023;
    float v = (k < 512) ? Wqf[(size_t)k * 512 + j] : Wql[(size_t)(k - 512) * 512 + j];
    wqT[t] = (f16)v;
  } else if (i < 1310720) {               // WcT
    int t = i - 1048576;
    int j = t >> 9, k = t & 511;
    wcT[t] = (f16)Wc[(size_t)k * 512 + j];
  }
}

// ---------------- generic GEMM: C(MxN) = A(MxK) * B(NxK)^T (+bias), fp16 out ----------------

__global__ __launch_bounds__(256, 2) void gemm_tn(
    const f16* __restrict__ A, const f16* __restrict__ B, f16* __restrict__ C,
    const float* __restrict__ bias, int M, int N, int K) {
  __shared__ f16 As[128 * 64];
  __shared__ f16 Bs[128 * 64];
  const int tid = threadIdx.x;
  const int wave = tid >> 6, lane = tid & 63;
  const int qd = lane >> 4, c = lane & 15;
  const int wm = wave >> 1, wn = wave & 1;
  const int m0 = blockIdx.x * 128, n0 = blockIdx.y * 128;
  const int srow = lane >> 3, sj = lane & 7;

  f32x4 acc[4][4];
#pragma unroll
  for (int i = 0; i < 4; ++i)
#pragma unroll
    for (int j = 0; j < 4; ++j) acc[i][j] = (f32x4){0.f, 0.f, 0.f, 0.f};

  for (int kc = 0; kc < K; kc += 64) {
#pragma unroll
    for (int i = 0; i < 4; ++i) {   // A: wave stages rows wave*32+i*8 .. +7
      int row = wave * 32 + i * 8 + srow;
      int gr = m0 + row; if (gr >= M) gr = M - 1;
      int gj = sj ^ (row & 7);
      gload16(A + (size_t)gr * K + kc + gj * 8, As + row * 64 + sj * 8);
    }
#pragma unroll
    for (int i = 0; i < 4; ++i) {   // B (N always multiple of 128)
      int row = wave * 32 + i * 8 + srow;
      int gj = sj ^ (row & 7);
      gload16(B + (size_t)(n0 + row) * K + kc + gj * 8, Bs + row * 64 + sj * 8);
    }
    __syncthreads();
#pragma unroll
    for (int kk = 0; kk < 2; ++kk) {
      f16x8 af[4], bf[4];
#pragma unroll
      for (int t = 0; t < 4; ++t) {
        int ra = wm * 64 + t * 16 + c;
        af[t] = *(const f16x8*)(As + ra * 64 + (((kk * 4 + qd) ^ (ra & 7)) * 8));
        int rb = wn * 64 + t * 16 + c;
        bf[t] = *(const f16x8*)(Bs + rb * 64 + (((kk * 4 + qd) ^ (rb & 7)) * 8));
      }
#pragma unroll
      for (int mt = 0; mt < 4; ++mt)
#pragma unroll
        for (int nt = 0; nt < 4; ++nt)
          acc[mt][nt] = __builtin_amdgcn_mfma_f32_16x16x32_f16(af[mt], bf[nt], acc[mt][nt], 0, 0, 0);
    }
    __syncthreads();
  }

#pragma unroll
  for (int mt = 0; mt < 4; ++mt) {
#pragma unroll
    for (int nt = 0; nt < 4; ++nt) {
      int col = n0 + wn * 64 + nt * 16 + c;
      float bv = bias ? bias[col] : 0.0f;
#pragma unroll
      for (int r = 0; r < 4; ++r) {
        int row = m0 + wm * 64 + mt * 16 + qd * 4 + r;
        if (row < M) C[(size_t)row * N + col] = (f16)(acc[mt][nt][r] + bv);
      }
    }
  }
}

// ---------------- fused multi-head attention (S^T formulation) ----------------
// grid = (b, h, quarter) = 64*16*4 blocks; 4 waves; each wave owns ONE 16-query-row tile.
// S^T = K·Q^T via mfma(A=K, B=Q): lane holds S^T[node=qd*4+r][qrow=c].
// softmax over node dim = in-register (13 tiles x 4 regs) + shfl_xor 16,32.
// P^T (C-layout) is directly the B-operand of mfma_f32_16x16x16f16:
// O^T = V^T · P^T, A = V^T fragments from LDS (stride 268). No P round-trip.

#define VSTR 268

__global__ __launch_bounds__(256, 4) void attn_kernel(
    const f16* __restrict__ Qp, const f16* __restrict__ KV,
    const float* __restrict__ mask, f16* __restrict__ Oc) {
  __shared__ f16 Vt[32 * VSTR];           // V^T[d][node], 17152 B
  const int bid = blockIdx.x;
  const int qq = bid & 3;
  const int h = (bid >> 2) & 15;
  const int b = bid >> 6;
  const int tid = threadIdx.x;
  const int wave = tid >> 6, lane = tid & 63;
  const int qd = lane >> 4, c = lane & 15;

  // stage V^T: thread handles (node m, d-chunk ch); writes 4 scalars Vt[4ch+k][m]
  for (int idx = tid; idx < 208 * 8; idx += 256) {
    int m = idx >> 3, ch = idx & 7;
    f16x4 v = (f16x4){0, 0, 0, 0};
    if (m < 201) v = *(const f16x4*)(KV + ((size_t)(b * NNODE + m)) * 1024 + 512 + h * 32 + ch * 4);
    Vt[(ch * 4 + 0) * VSTR + m] = v.x;
    Vt[(ch * 4 + 1) * VSTR + m] = v.y;
    Vt[(ch * 4 + 2) * VSTR + m] = v.z;
    Vt[(ch * 4 + 3) * VSTR + m] = v.w;
  }
  __syncthreads();

  const int start = (qq == 0) ? 0 : (1 + 3 * qq);     // {0,4,7,10}
  const int ntile = (qq == 0) ? 4 : 3;
  const int rt = start + wave;
  if (wave >= ntile) return;

  const int r0 = rt * 16;
  const int qrow = min(r0 + c, 199);
  const float scale = 0.17677669529663687f;           // 1/sqrt(32)

  // Q fragment (B-operand): lane holds qrow=c, k=qd*8+j
  f16x8 aq = *(const f16x8*)(Qp + ((size_t)(b * NPOMO + qrow)) * 512 + h * 32 + qd * 8);

  // S^T = K·Q^T
  f32x4 s[13];
#pragma unroll
  for (int nt = 0; nt < 13; ++nt) {
    int node = nt * 16 + c; if (node > 200) node = 200;
    f16x8 ak = *(const f16x8*)(KV + ((size_t)(b * NNODE + node)) * 1024 + h * 32 + qd * 8);
    f32x4 z = (f32x4){0.f, 0.f, 0.f, 0.f};
    s[nt] = __builtin_amdgcn_mfma_f32_16x16x32_f16(ak, aq, z, 0, 0, 0);
  }

  // scale + mask (float4 per tile: 4 consecutive mask cols = the 4 regs)
  float mx = -3e38f;
#pragma unroll
  for (int nt = 0; nt < 13; ++nt) {
    const int col0 = nt * 16 + qd * 4;
    float4 mv = make_float4(0.f, 0.f, 0.f, 0.f);
    if (col0 < 200)
      mv = *(const float4*)(mask + ((size_t)b * NPOMO + qrow) * 200 + col0);
#pragma unroll
    for (int r = 0; r < 4; ++r) {
      int node = col0 + r;
      float v;
      if (node > 200)      v = -3e38f;
      else if (node == 200) v = s[nt][r] * scale;
      else                  v = s[nt][r] * scale + ((const float*)&mv)[r];
      s[nt][r] = v;
      mx = fmaxf(mx, v);
    }
  }
  mx = fmaxf(mx, __shfl_xor(mx, 16));
  mx = fmaxf(mx, __shfl_xor(mx, 32));

  float sm = 0.f;
  f16x4 pf[13];
#pragma unroll
  for (int nt = 0; nt < 13; ++nt) {
    f16x4 p4;
#pragma unroll
    for (int r = 0; r < 4; ++r) {
      float p = __expf(s[nt][r] - mx);
      sm += p;
      p4[r] = (f16)p;
    }
    pf[nt] = p4;
  }
  sm += __shfl_xor(sm, 16);
  sm += __shfl_xor(sm, 32);
  const float inv = 1.0f / sm;

  // O^T = V^T · P^T  (16x16x16 mfma, two d-halves)
  f32x4 o0 = (f32x4){0.f, 0.f, 0.f, 0.f};
  f32x4 o1 = (f32x4){0.f, 0.f, 0.f, 0.f};
#pragma unroll
  for (int nt = 0; nt < 13; ++nt) {
    const int nb = nt * 16 + qd * 4;
    f16x4 av0 = *(const f16x4*)(Vt + c * VSTR + nb);
    f16x4 av1 = *(const f16x4*)(Vt + (c + 16) * VSTR + nb);
    o0 = __builtin_amdgcn_mfma_f32_16x16x16f16(av0, pf[nt], o0, 0, 0, 0);
    o1 = __builtin_amdgcn_mfma_f32_16x16x16f16(av1, pf[nt], o1, 0, 0, 0);
  }

  const int row = r0 + c;
  if (row < 200) {
    f16* dst = Oc + ((size_t)(b * NPOMO + row)) * 512 + h * 32 + qd * 4;
    f16x4 w0 = {(f16)(o0[0] * inv), (f16)(o0[1] * inv), (f16)(o0[2] * inv), (f16)(o0[3] * inv)};
    f16x4 w1 = {(f16)(o1[0] * inv), (f16)(o1[1] * inv), (f16)(o1[2] * inv), (f16)(o1[3] * inv)};
    *(f16x4*)dst = w0;
    *(f16x4*)(dst + 16) = w1;
  }
}

// ---------------- final: score2 -> 10*tanh + mask -> softmax ----------------

__global__ __launch_bounds__(256, 2) void final_kernel(
    const f16* __restrict__ mh, const f16* __restrict__ Xnh,
    const float* __restrict__ mask, float* __restrict__ out) {
  __shared__ f16 As[64 * 72];
  __shared__ f16 Bs[208 * 72];
  const int b = blockIdx.x >> 2, rb = blockIdx.x & 3;
  const int r0 = rb * 64;
  const int tid = threadIdx.x;
  const int wave = tid >> 6, lane = tid & 63;
  const int qd = lane >> 4, c = lane & 15;

  f32x4 acc[13];
#pragma unroll
  for (int i = 0; i < 13; ++i) acc[i] = (f32x4){0.f, 0.f, 0.f, 0.f};

  for (int kc = 0; kc < 512; kc += 64) {
    for (int idx = tid; idx < 64 * 16; idx += 256) {
      int row = idx >> 4, ch = idx & 15;
      int gr = r0 + row; if (gr > 199) gr = 199;
      *(f16x4*)(As + row * 72 + ch * 4) =
          *(const f16x4*)(mh + ((size_t)b * NPOMO + gr) * 512 + kc + ch * 4);
    }
    for (int idx = tid; idx < 208 * 16; idx += 256) {
      int n = idx >> 4, ch = idx & 15;
      f16x4 v = (f16x4){0, 0, 0, 0};
      if (n < 200) v = *(const f16x4*)(Xnh + ((size_t)b * NNODE + n) * 512 + kc + ch * 4);
      *(f16x4*)(Bs + n * 72 + ch * 4) = v;
    }
    __syncthreads();
#pragma unroll
    for (int kk = 0; kk < 2; ++kk) {
      f16x8 a = *(const f16x8*)(As + (wave * 16 + c) * 72 + kk * 32 + qd * 8);
#pragma unroll
      for (int nt = 0; nt < 13; ++nt) {
        f16x8 bb = *(const f16x8*)(Bs + (nt * 16 + c) * 72 + kk * 32 + qd * 8);
        acc[nt] = __builtin_amdgcn_mfma_f32_16x16x32_f16(a, bb, acc[nt], 0, 0, 0);
      }
    }
    __syncthreads();
  }

  const float invS = 1.0f / 22.627416997969522f;
  const int rowb = r0 + wave * 16 + qd * 4;
  float mx[4] = {-3e38f, -3e38f, -3e38f, -3e38f};
#pragma unroll
  for (int nt = 0; nt < 13; ++nt) {
    int col = nt * 16 + c;
#pragma unroll
    for (int r = 0; r < 4; ++r) {
      float v;
      if (col < 200) {
        v = 10.0f * tanhf(acc[nt][r] * invS);
        int rr = rowb + r;
        if (rr < 200) v += mask[((size_t)b * NPOMO + rr) * 200 + col];
      } else {
        v = -3e38f;
      }
      acc[nt][r] = v;
      mx[r] = fmaxf(mx[r], v);
    }
  }
#pragma unroll
  for (int off = 8; off >= 1; off >>= 1)
#pragma unroll
    for (int r = 0; r < 4; ++r) mx[r] = fmaxf(mx[r], __shfl_xor(mx[r], off, 16));
  float sm[4] = {0.f, 0.f, 0.f, 0.f};
#pragma unroll
  for (int nt = 0; nt < 13; ++nt)
#pragma unroll
    for (int r = 0; r < 4; ++r) {
      float p = __expf(acc[nt][r] - mx[r]);
      acc[nt][r] = p;
      sm[r] += p;
    }
#pragma unroll
  for (int off = 8; off >= 1; off >>= 1)
#pragma unroll
    for (int r = 0; r < 4; ++r) sm[r] += __shfl_xor(sm[r], off, 16);
  float inv[4];
#pragma unroll
  for (int r = 0; r < 4; ++r) inv[r] = 1.0f / sm[r];
#pragma unroll
  for (int nt = 0; nt < 13; ++nt) {
    int col = nt * 16 + c;
#pragma unroll
    for (int r = 0; r < 4; ++r) {
      int rr = rowb + r;
      if (col < 200 && rr < 200)
        out[((size_t)b * NPOMO + rr) * 200 + col] = acc[nt][r] * inv[r];
    }
  }
}

// ---------------- launcher ----------------

extern "C" void kernel_launch(void* const* d_in, const int* in_sizes, int n_in,
                              void* d_out, int out_size, void* d_ws, size_t ws_size,
                              hipStream_t stream) {
  (void)in_sizes; (void)n_in; (void)out_size; (void)ws_size;
  const float* enc   = (const float*)d_in[0];
  const float* q1    = (const float*)d_in[1];
  const float* qlast = (const float*)d_in[2];
  const float* mask  = (const float*)d_in[3];
  const float* Wqf   = (const float*)d_in[4];
  const float* Wql   = (const float*)d_in[5];
  const float* Wk    = (const float*)d_in[6];
  const float* Wv    = (const float*)d_in[7];
  const float* Wc    = (const float*)d_in[8];
  const float* bc    = (const float*)d_in[9];
  float* out = (float*)d_out;

  char* ws = (char*)d_ws;
  f16* Xnh  = (f16*)(ws + 0);           // 12864*512*2  = 13,172,736
  f16* Qcat = (f16*)(ws + 13172736);    // 12800*1024*2 = 26,214,400
  f16* WkvT = (f16*)(ws + 39387136);    // 1024*512*2   =  1,048,576
  f16* WqT  = (f16*)(ws + 40435712);    // 512*1024*2   =  1,048,576
  f16* WcT  = (f16*)(ws + 41484288);    // 512*512*2    =    524,288
  f16* KVp  = (f16*)(ws + 42008576);    // 12864*1024*2 = 26,345,472
  f16* Qp   = (f16*)(ws + 68354048);    // 12800*512*2  = 13,107,200
  f16* Oc   = (f16*)(ws + 81461248);    // 12800*512*2  = 13,107,200
  f16* mhb  = (f16*)(ws + 94568448);    // 12800*512*2  = 13,107,200  (end 107,675,648)

  hipLaunchKernelGGL(cast_x, dim3(6432), dim3(256), 0, stream, enc, Xnh, 1646592);
  hipLaunchKernelGGL(build_qcat, dim3(12800), dim3(256), 0, stream, q1, qlast, Qcat);
  hipLaunchKernelGGL(build_w, dim3(5120), dim3(256), 0, stream, Wk, Wv, Wqf, Wql, Wc, WkvT, WqT, WcT);
  // K,V projection: (12864x512) @ (1024x512)^T -> 12864x1024 (cols 0..511=K, 512..1023=V)
  hipLaunchKernelGGL(gemm_tn, dim3(101, 8), dim3(256), 0, stream,
                     Xnh, WkvT, KVp, (const float*)nullptr, 12864, 1024, 512);
  // Q projection: (12800x1024) @ (512x1024)^T -> 12800x512
  hipLaunchKernelGGL(gemm_tn, dim3(100, 4), dim3(256), 0, stream,
                     Qcat, WqT, Qp, (const float*)nullptr, 12800, 512, 1024);
  hipLaunchKernelGGL(attn_kernel, dim3(4096), dim3(256), 0, stream, Qp, KVp, mask, Oc);
  // Wc projection + bias: (12800x512) @ (512x512)^T + bc -> 12800x512
  hipLaunchKernelGGL(gemm_tn, dim3(100, 4), dim3(256), 0, stream,
                     Oc, WcT, mhb, bc, 12800, 512, 512);
  hipLaunchKernelGGL(final_kernel, dim3(256), dim3(256), 0, stream, mhb, Xnh, mask, out);
}

// Round 3
// 316.177 us; speedup vs baseline: 1.3835x; 1.1119x over previous
//
#include <hip/hip_runtime.h>
#include <cstdint>
#include <cstddef>

typedef _Float16 f16;
typedef f16 f16x4 __attribute__((ext_vector_type(4)));
typedef f16 f16x8 __attribute__((ext_vector_type(8)));
typedef float f32x4 __attribute__((ext_vector_type(4)));

#define NB    64      // batch
#define NPOMO 200
#define NNODE 201
#define NEMB  512
#define NH    16
#define ND    32

__device__ __forceinline__ void gload16(const void* g, void* l) {
  __builtin_amdgcn_global_load_lds((const __attribute__((address_space(1))) void*)g,
                                   (__attribute__((address_space(3))) void*)l, 16, 0, 0);
}

// ---------------- cast / layout kernels ----------------

__global__ void cast_x(const float* __restrict__ x, f16* __restrict__ o, int n4) {
  int i = blockIdx.x * 256 + threadIdx.x;
  if (i < n4) {
    float4 v = ((const float4*)x)[i];
    f16x4 h = {(f16)v.x, (f16)v.y, (f16)v.z, (f16)v.w};
    ((f16x4*)o)[i] = h;
  }
}

// Qcat: (12800 x 1024) fp16, cols 0..511 = encoded_q1 row, 512..1023 = encoded_last_node row
__global__ void build_qcat(const float* __restrict__ q1, const float* __restrict__ ql,
                           f16* __restrict__ o) {
  int i = blockIdx.x * 256 + threadIdx.x;   // over 4-element groups; 12800*256 total
  if (i >= 12800 * 256) return;
  int row = i >> 8;
  int g = i & 255;
  const float* src = (g < 128) ? (q1 + (size_t)row * 512 + g * 4)
                               : (ql + (size_t)row * 512 + (g - 128) * 4);
  float4 v = *(const float4*)src;
  f16x4 h = {(f16)v.x, (f16)v.y, (f16)v.z, (f16)v.w};
  ((f16x4*)o)[i] = h;
}

// WkvT (1024x512): row j<512 -> Wk[:,j]; j>=512 -> Wv[:,j-512]
// WqcatT (512x1024): [j][k] = k<512 ? Wqf[k][j] : Wql[k-512][j]
// WcT (512x512): [j][k] = Wc[k][j]
__global__ void build_w(const float* __restrict__ Wk, const float* __restrict__ Wv,
                        const float* __restrict__ Wqf, const float* __restrict__ Wql,
                        const float* __restrict__ Wc,
                        f16* __restrict__ wkvT, f16* __restrict__ wqT, f16* __restrict__ wcT) {
  int i = blockIdx.x * 256 + threadIdx.x;
  if (i < 524288) {                       // WkvT
    int j = i >> 9, k = i & 511;
    float v = (j < 512) ? Wk[(size_t)k * 512 + j] : Wv[(size_t)k * 512 + (j - 512)];
    wkvT[i] = (f16)v;
  } else if (i < 1048576) {               // WqcatT
    int t = i - 524288;
    int j = t >> 10, k = t & 1023;
    float v = (k < 512) ? Wqf[(size_t)k * 512 + j] : Wql[(size_t)(k - 512) * 512 + j];
    wqT[t] = (f16)v;
  } else if (i < 1310720) {               // WcT
    int t = i - 1048576;
    int j = t >> 9, k = t & 511;
    wcT[t] = (f16)Wc[(size_t)k * 512 + j];
  }
}

// ---------------- generic GEMM: C(MxN) = A(MxK) * B(NxK)^T (+bias), fp16 out ----------------

__global__ __launch_bounds__(256, 2) void gemm_tn(
    const f16* __restrict__ A, const f16* __restrict__ B, f16* __restrict__ C,
    const float* __restrict__ bias, int M, int N, int K) {
  __shared__ f16 As[128 * 64];
  __shared__ f16 Bs[128 * 64];
  const int tid = threadIdx.x;
  const int wave = tid >> 6, lane = tid & 63;
  const int qd = lane >> 4, c = lane & 15;
  const int wm = wave >> 1, wn = wave & 1;
  const int m0 = blockIdx.x * 128, n0 = blockIdx.y * 128;
  const int srow = lane >> 3, sj = lane & 7;

  f32x4 acc[4][4];
#pragma unroll
  for (int i = 0; i < 4; ++i)
#pragma unroll
    for (int j = 0; j < 4; ++j) acc[i][j] = (f32x4){0.f, 0.f, 0.f, 0.f};

  for (int kc = 0; kc < K; kc += 64) {
#pragma unroll
    for (int i = 0; i < 4; ++i) {   // A: wave stages rows wave*32+i*8 .. +7
      int row = wave * 32 + i * 8 + srow;
      int gr = m0 + row; if (gr >= M) gr = M - 1;
      int gj = sj ^ (row & 7);
      gload16(A + (size_t)gr * K + kc + gj * 8, As + row * 64 + sj * 8);
    }
#pragma unroll
    for (int i = 0; i < 4; ++i) {   // B (N always multiple of 128)
      int row = wave * 32 + i * 8 + srow;
      int gj = sj ^ (row & 7);
      gload16(B + (size_t)(n0 + row) * K + kc + gj * 8, Bs + row * 64 + sj * 8);
    }
    __syncthreads();
#pragma unroll
    for (int kk = 0; kk < 2; ++kk) {
      f16x8 af[4], bf[4];
#pragma unroll
      for (int t = 0; t < 4; ++t) {
        int ra = wm * 64 + t * 16 + c;
        af[t] = *(const f16x8*)(As + ra * 64 + (((kk * 4 + qd) ^ (ra & 7)) * 8));
        int rb = wn * 64 + t * 16 + c;
        bf[t] = *(const f16x8*)(Bs + rb * 64 + (((kk * 4 + qd) ^ (rb & 7)) * 8));
      }
#pragma unroll
      for (int mt = 0; mt < 4; ++mt)
#pragma unroll
        for (int nt = 0; nt < 4; ++nt)
          acc[mt][nt] = __builtin_amdgcn_mfma_f32_16x16x32_f16(af[mt], bf[nt], acc[mt][nt], 0, 0, 0);
    }
    __syncthreads();
  }

#pragma unroll
  for (int mt = 0; mt < 4; ++mt) {
#pragma unroll
    for (int nt = 0; nt < 4; ++nt) {
      int col = n0 + wn * 64 + nt * 16 + c;
      float bv = bias ? bias[col] : 0.0f;
#pragma unroll
      for (int r = 0; r < 4; ++r) {
        int row = m0 + wm * 64 + mt * 16 + qd * 4 + r;
        if (row < M) C[(size_t)row * N + col] = (f16)(acc[mt][nt][r] + bv);
      }
    }
  }
}

// ---------------- fused multi-head attention (S^T formulation) ----------------

#define VSTR 268

__global__ __launch_bounds__(256, 4) void attn_kernel(
    const f16* __restrict__ Qp, const f16* __restrict__ KV,
    const float* __restrict__ mask, f16* __restrict__ Oc) {
  __shared__ f16 Vt[32 * VSTR];           // V^T[d][node], 17152 B
  const int bid = blockIdx.x;
  const int qq = bid & 3;
  const int h = (bid >> 2) & 15;
  const int b = bid >> 6;
  const int tid = threadIdx.x;
  const int wave = tid >> 6, lane = tid & 63;
  const int qd = lane >> 4, c = lane & 15;

  for (int idx = tid; idx < 208 * 8; idx += 256) {
    int m = idx >> 3, ch = idx & 7;
    f16x4 v = (f16x4){0, 0, 0, 0};
    if (m < 201) v = *(const f16x4*)(KV + ((size_t)(b * NNODE + m)) * 1024 + 512 + h * 32 + ch * 4);
    Vt[(ch * 4 + 0) * VSTR + m] = v.x;
    Vt[(ch * 4 + 1) * VSTR + m] = v.y;
    Vt[(ch * 4 + 2) * VSTR + m] = v.z;
    Vt[(ch * 4 + 3) * VSTR + m] = v.w;
  }
  __syncthreads();

  const int start = (qq == 0) ? 0 : (1 + 3 * qq);     // {0,4,7,10}
  const int ntile = (qq == 0) ? 4 : 3;
  const int rt = start + wave;
  if (wave >= ntile) return;

  const int r0 = rt * 16;
  const int qrow = min(r0 + c, 199);
  const float scale = 0.17677669529663687f;           // 1/sqrt(32)

  f16x8 aq = *(const f16x8*)(Qp + ((size_t)(b * NPOMO + qrow)) * 512 + h * 32 + qd * 8);

  f32x4 s[13];
#pragma unroll
  for (int nt = 0; nt < 13; ++nt) {
    int node = nt * 16 + c; if (node > 200) node = 200;
    f16x8 ak = *(const f16x8*)(KV + ((size_t)(b * NNODE + node)) * 1024 + h * 32 + qd * 8);
    f32x4 z = (f32x4){0.f, 0.f, 0.f, 0.f};
    s[nt] = __builtin_amdgcn_mfma_f32_16x16x32_f16(ak, aq, z, 0, 0, 0);
  }

  float mx = -3e38f;
#pragma unroll
  for (int nt = 0; nt < 13; ++nt) {
    const int col0 = nt * 16 + qd * 4;
    float4 mv = make_float4(0.f, 0.f, 0.f, 0.f);
    if (col0 < 200)
      mv = *(const float4*)(mask + ((size_t)b * NPOMO + qrow) * 200 + col0);
#pragma unroll
    for (int r = 0; r < 4; ++r) {
      int node = col0 + r;
      float v;
      if (node > 200)      v = -3e38f;
      else if (node == 200) v = s[nt][r] * scale;
      else                  v = s[nt][r] * scale + ((const float*)&mv)[r];
      s[nt][r] = v;
      mx = fmaxf(mx, v);
    }
  }
  mx = fmaxf(mx, __shfl_xor(mx, 16));
  mx = fmaxf(mx, __shfl_xor(mx, 32));

  float sm = 0.f;
  f16x4 pf[13];
#pragma unroll
  for (int nt = 0; nt < 13; ++nt) {
    f16x4 p4;
#pragma unroll
    for (int r = 0; r < 4; ++r) {
      float p = __expf(s[nt][r] - mx);
      sm += p;
      p4[r] = (f16)p;
    }
    pf[nt] = p4;
  }
  sm += __shfl_xor(sm, 16);
  sm += __shfl_xor(sm, 32);
  const float inv = 1.0f / sm;

  f32x4 o0 = (f32x4){0.f, 0.f, 0.f, 0.f};
  f32x4 o1 = (f32x4){0.f, 0.f, 0.f, 0.f};
#pragma unroll
  for (int nt = 0; nt < 13; ++nt) {
    const int nb = nt * 16 + qd * 4;
    f16x4 av0 = *(const f16x4*)(Vt + c * VSTR + nb);
    f16x4 av1 = *(const f16x4*)(Vt + (c + 16) * VSTR + nb);
    o0 = __builtin_amdgcn_mfma_f32_16x16x16f16(av0, pf[nt], o0, 0, 0, 0);
    o1 = __builtin_amdgcn_mfma_f32_16x16x16f16(av1, pf[nt], o1, 0, 0, 0);
  }

  const int row = r0 + c;
  if (row < 200) {
    f16* dst = Oc + ((size_t)(b * NPOMO + row)) * 512 + h * 32 + qd * 4;
    f16x4 w0 = {(f16)(o0[0] * inv), (f16)(o0[1] * inv), (f16)(o0[2] * inv), (f16)(o0[3] * inv)};
    f16x4 w1 = {(f16)(o1[0] * inv), (f16)(o1[1] * inv), (f16)(o1[2] * inv), (f16)(o1[3] * inv)};
    *(f16x4*)dst = w0;
    *(f16x4*)(dst + 16) = w1;
  }
}

// ---------------- final: score2^T -> 10*tanh + mask -> softmax (no-LDS GEMM) ----------------
// grid = 64 batches x 13 row-tiles (16 rows). 4 waves split the 13 node-tiles (4/3/3/3),
// each runs full K=512 reading A (Xnh node rows) and B (mh rows) straight from global.
// Lane layout: row = c, node = nt*16 + qd*4 + r. Softmax over nodes: in-register +
// shfl_xor(16,32) + tiny LDS cross-wave exchange (max, sum). float4 mask load / out store.

__global__ __launch_bounds__(256, 4) void final_kernel(
    const f16* __restrict__ mh, const f16* __restrict__ Xnh,
    const float* __restrict__ mask, float* __restrict__ out) {
  __shared__ float xmax[4][16];
  __shared__ float xsum[4][16];
  const int b = blockIdx.x / 13;
  const int tile = blockIdx.x % 13;
  const int r0 = tile * 16;
  const int tid = threadIdx.x;
  const int wave = tid >> 6, lane = tid & 63;
  const int qd = lane >> 4, c = lane & 15;

  const int nt0 = (wave == 0) ? 0 : (3 * wave + 1);   // {0,4,7,10}
  const int cnt = (wave == 0) ? 4 : 3;

  const int qrow = min(r0 + c, 199);
  const size_t rbase = ((size_t)(b * NPOMO + qrow)) * 512;

  size_t abase[4];
#pragma unroll
  for (int i = 0; i < 4; ++i) {
    int nt = nt0 + i;
    int nd = nt * 16 + c; if (nd > 200) nd = 200;
    abase[i] = ((size_t)(b * NNODE + nd)) * 512;
  }

  f32x4 acc[4];
#pragma unroll
  for (int i = 0; i < 4; ++i) acc[i] = (f32x4){0.f, 0.f, 0.f, 0.f};

#pragma unroll 4
  for (int kc = 0; kc < 512; kc += 32) {
    f16x8 bq = *(const f16x8*)(mh + rbase + kc + qd * 8);
#pragma unroll
    for (int i = 0; i < 4; ++i) {
      if (i < cnt) {
        f16x8 a = *(const f16x8*)(Xnh + abase[i] + kc + qd * 8);
        acc[i] = __builtin_amdgcn_mfma_f32_16x16x32_f16(a, bq, acc[i], 0, 0, 0);
      }
    }
  }

  const float invS = 1.0f / 22.627416997969522f;
  float mx = -3e38f;
#pragma unroll
  for (int i = 0; i < 4; ++i) {
    if (i >= cnt) break;
    const int nt = nt0 + i;
    const int col0 = nt * 16 + qd * 4;
    float4 mv = make_float4(0.f, 0.f, 0.f, 0.f);
    if (col0 < 200)
      mv = *(const float4*)(mask + ((size_t)b * NPOMO + qrow) * 200 + col0);
#pragma unroll
    for (int r = 0; r < 4; ++r) {
      int node = col0 + r;
      float v;
      if (node < 200) {
        float t = __expf(2.0f * acc[i][r] * invS);
        float th = 1.0f - 2.0f / (t + 1.0f);
        v = 10.0f * th + ((const float*)&mv)[r];
      } else {
        v = -3e38f;
      }
      acc[i][r] = v;
      mx = fmaxf(mx, v);
    }
  }
  mx = fmaxf(mx, __shfl_xor(mx, 16));
  mx = fmaxf(mx, __shfl_xor(mx, 32));
  if (lane < 16) xmax[wave][lane] = mx;
  __syncthreads();
  mx = fmaxf(fmaxf(xmax[0][c], xmax[1][c]), fmaxf(xmax[2][c], xmax[3][c]));

  float sm = 0.f;
#pragma unroll
  for (int i = 0; i < 4; ++i) {
    if (i >= cnt) break;
#pragma unroll
    for (int r = 0; r < 4; ++r) {
      float p = __expf(acc[i][r] - mx);
      acc[i][r] = p;
      sm += p;
    }
  }
  sm += __shfl_xor(sm, 16);
  sm += __shfl_xor(sm, 32);
  if (lane < 16) xsum[wave][lane] = sm;
  __syncthreads();
  const float tot = xsum[0][c] + xsum[1][c] + xsum[2][c] + xsum[3][c];
  const float inv = 1.0f / tot;

  const int row = r0 + c;
  if (row < 200) {
#pragma unroll
    for (int i = 0; i < 4; ++i) {
      if (i >= cnt) break;
      const int col0 = (nt0 + i) * 16 + qd * 4;
      if (col0 < 200) {
        float4 o;
        o.x = acc[i][0] * inv; o.y = acc[i][1] * inv;
        o.z = acc[i][2] * inv; o.w = acc[i][3] * inv;
        *(float4*)(out + ((size_t)b * NPOMO + row) * 200 + col0) = o;
      }
    }
  }
}

// ---------------- launcher ----------------

extern "C" void kernel_launch(void* const* d_in, const int* in_sizes, int n_in,
                              void* d_out, int out_size, void* d_ws, size_t ws_size,
                              hipStream_t stream) {
  (void)in_sizes; (void)n_in; (void)out_size; (void)ws_size;
  const float* enc   = (const float*)d_in[0];
  const float* q1    = (const float*)d_in[1];
  const float* qlast = (const float*)d_in[2];
  const float* mask  = (const float*)d_in[3];
  const float* Wqf   = (const float*)d_in[4];
  const float* Wql   = (const float*)d_in[5];
  const float* Wk    = (const float*)d_in[6];
  const float* Wv    = (const float*)d_in[7];
  const float* Wc    = (const float*)d_in[8];
  const float* bc    = (const float*)d_in[9];
  float* out = (float*)d_out;

  char* ws = (char*)d_ws;
  f16* Xnh  = (f16*)(ws + 0);           // 12864*512*2  = 13,172,736
  f16* Qcat = (f16*)(ws + 13172736);    // 12800*1024*2 = 26,214,400
  f16* WkvT = (f16*)(ws + 39387136);    // 1024*512*2   =  1,048,576
  f16* WqT  = (f16*)(ws + 40435712);    // 512*1024*2   =  1,048,576
  f16* WcT  = (f16*)(ws + 41484288);    // 512*512*2    =    524,288
  f16* KVp  = (f16*)(ws + 42008576);    // 12864*1024*2 = 26,345,472
  f16* Qp   = (f16*)(ws + 68354048);    // 12800*512*2  = 13,107,200
  f16* Oc   = (f16*)(ws + 81461248);    // 12800*512*2  = 13,107,200
  f16* mhb  = (f16*)(ws + 94568448);    // 12800*512*2  = 13,107,200  (end 107,675,648)

  hipLaunchKernelGGL(cast_x, dim3(6432), dim3(256), 0, stream, enc, Xnh, 1646592);
  hipLaunchKernelGGL(build_qcat, dim3(12800), dim3(256), 0, stream, q1, qlast, Qcat);
  hipLaunchKernelGGL(build_w, dim3(5120), dim3(256), 0, stream, Wk, Wv, Wqf, Wql, Wc, WkvT, WqT, WcT);
  hipLaunchKernelGGL(gemm_tn, dim3(101, 8), dim3(256), 0, stream,
                     Xnh, WkvT, KVp, (const float*)nullptr, 12864, 1024, 512);
  hipLaunchKernelGGL(gemm_tn, dim3(100, 4), dim3(256), 0, stream,
                     Qcat, WqT, Qp, (const float*)nullptr, 12800, 512, 1024);
  hipLaunchKernelGGL(attn_kernel, dim3(4096), dim3(256), 0, stream, Qp, KVp, mask, Oc);
  hipLaunchKernelGGL(gemm_tn, dim3(100, 4), dim3(256), 0, stream,
                     Oc, WcT, mhb, bc, 12800, 512, 512);
  hipLaunchKernelGGL(final_kernel, dim3(832), dim3(256), 0, stream, mhb, Xnh, mask, out);
}